// Round 1
// baseline (939.699 us; speedup 1.0000x reference)
//
#include <hip/hip_runtime.h>
#include <hip/hip_bf16.h>
#include <stdint.h>

// ---------- helpers ----------
typedef __attribute__((ext_vector_type(8))) short short8;   // 8 bf16 (A/B frag)
typedef __attribute__((ext_vector_type(4))) float f32x4;    // C/D frag

__device__ __forceinline__ uint16_t f2bf(float x) {
    union { float f; uint32_t u; } un; un.f = x;
    uint32_t u = un.u;
    uint32_t r = (u + 0x7fffu + ((u >> 16) & 1u)) >> 16;   // RNE
    return (uint16_t)r;
}
__device__ __forceinline__ float bf2f(uint32_t bits16) {
    union { uint32_t u; float f; } un; un.u = bits16 << 16; return un.f;
}
__device__ __forceinline__ float wave_reduce_add(float v) {
    #pragma unroll
    for (int off = 32; off >= 1; off >>= 1) v += __shfl_xor(v, off);
    return v;
}

#define DIM 128

// ---------- CSR build ----------
__global__ void count_kernel(const int* __restrict__ dst, int* __restrict__ cnt, int E) {
    int e = blockIdx.x * blockDim.x + threadIdx.x;
    if (e < E) atomicAdd(&cnt[dst[e]], 1);
}

#define SCAN_CHUNK 2048
__global__ void scan1_kernel(const int* __restrict__ cnt, int* __restrict__ row_start,
                             int* __restrict__ bsums, int N) {
    __shared__ int lds[256];
    int tid = threadIdx.x;
    int base = blockIdx.x * SCAN_CHUNK;
    int vals[8]; int s = 0;
    #pragma unroll
    for (int i = 0; i < 8; i++) {
        int idx = base + tid * 8 + i;
        int v = (idx < N) ? cnt[idx] : 0;
        vals[i] = s; s += v;                 // local exclusive prefix
    }
    lds[tid] = s; __syncthreads();
    for (int off = 1; off < 256; off <<= 1) {
        int x = 0; if (tid >= off) x = lds[tid - off];
        __syncthreads();
        lds[tid] += x;
        __syncthreads();
    }
    int texcl = (tid > 0) ? lds[tid - 1] : 0;
    #pragma unroll
    for (int i = 0; i < 8; i++) {
        int idx = base + tid * 8 + i;
        if (idx < N) row_start[idx] = texcl + vals[i];
    }
    if (tid == 255) bsums[blockIdx.x] = lds[255];
}
__global__ void scan2_kernel(int* __restrict__ bsums, int nb) {
    if (threadIdx.x == 0 && blockIdx.x == 0) {
        int s = 0;
        for (int i = 0; i < nb; i++) { int v = bsums[i]; bsums[i] = s; s += v; }
    }
}
__global__ void scan3_kernel(int* __restrict__ row_start, int* __restrict__ cursor,
                             const int* __restrict__ bsums, int N, int E) {
    int idx = blockIdx.x * blockDim.x + threadIdx.x;
    if (idx < N) {
        int v = row_start[idx] + bsums[idx / SCAN_CHUNK];
        row_start[idx] = v;
        cursor[idx] = v;
    }
    if (idx == 0) row_start[N] = E;
}
__global__ void scatter_kernel(const int* __restrict__ src, const int* __restrict__ dst,
                               int* __restrict__ cursor, int* __restrict__ esrc, int E) {
    int e = blockIdx.x * blockDim.x + threadIdx.x;
    if (e < E) {
        int d = dst[e];
        int pos = atomicAdd(&cursor[d], 1);
        esrc[pos] = src[e];
    }
}

// ---------- weight conversion fp32 -> bf16, layout [l][mat][row n][k] ----------
__global__ void convert_w_kernel(const float* __restrict__ Wq, const float* __restrict__ Wk,
                                 const float* __restrict__ Wv, uint16_t* __restrict__ wout,
                                 int total /* L*3*128*128 */) {
    int tid = blockIdx.x * blockDim.x + threadIdx.x;
    if (tid >= total) return;
    int per_l = 3 * DIM * DIM;
    int l = tid / per_l;
    int rem = tid % per_l;
    int mat = rem / (DIM * DIM);
    int idx = rem % (DIM * DIM);
    const float* s = (mat == 0) ? Wq : (mat == 1) ? Wk : Wv;
    wout[tid] = f2bf(s[l * DIM * DIM + idx]);
}

// ---------- tangent: t = (2/sc) * atanh(sc*||x||) * x/||x||, bf16 out ----------
__global__ __launch_bounds__(256) void tangent_kernel(const float* __restrict__ x,
                                                      uint16_t* __restrict__ t,
                                                      const float* __restrict__ curv, int N) {
    int wave = threadIdx.x >> 6, lane = threadIdx.x & 63;
    int n = blockIdx.x * 4 + wave;
    if (n >= N) return;
    float2 xv = ((const float2*)(x + (size_t)n * DIM))[lane];
    float ss = xv.x * xv.x + xv.y * xv.y;
    ss = wave_reduce_add(ss);
    float c = curv[0];
    float sc = sqrtf(c);
    float r = sqrtf(ss);
    float f = (r > 1e-30f) ? (2.0f / sc) * atanhf(sc * r) / r : 2.0f;
    uint32_t pk = (uint32_t)f2bf(f * xv.x) | ((uint32_t)f2bf(f * xv.y) << 16);
    ((uint32_t*)t)[(size_t)n * (DIM / 2) + lane] = pk;
}

// ---------- fused QKV GEMM: [N,128] x [128,384] via 16x16x32 bf16 MFMA ----------
__global__ __launch_bounds__(256) void qkv_gemm_kernel(
    const uint16_t* __restrict__ t,    // [N,128] bf16
    const uint16_t* __restrict__ w,    // [3][128][128] bf16 (this layer)
    const float* __restrict__ bq, const float* __restrict__ bk, const float* __restrict__ bv,
    uint16_t* __restrict__ q, uint16_t* __restrict__ k, uint16_t* __restrict__ v,
    int N) {
    int wave = threadIdx.x >> 6, lane = threadIdx.x & 63;
    int strip = blockIdx.x * 4 + wave;          // 16-row strip
    int row0 = strip * 16;
    int gy = blockIdx.y;                        // 0..5, 64-col group of the 384 cols
    int mat = gy >> 1;
    int colbase = (gy & 1) * 64;
    const uint16_t* wm = w + (size_t)mat * DIM * DIM;
    const float* bias = (mat == 0) ? bq : (mat == 1) ? bk : bv;
    uint16_t* outp = (mat == 0) ? q : (mat == 1) ? k : v;
    int m = lane & 15;
    int quad = lane >> 4;
    int arow = row0 + m;
    int arowc = (arow < N) ? arow : (N - 1);
    f32x4 acc[4] = {};
    #pragma unroll
    for (int k0 = 0; k0 < DIM; k0 += 32) {
        short8 a = *(const short8*)(t + (size_t)arowc * DIM + k0 + quad * 8);
        #pragma unroll
        for (int ct = 0; ct < 4; ct++) {
            int col = colbase + ct * 16 + m;
            short8 b = *(const short8*)(wm + (size_t)col * DIM + k0 + quad * 8);
            acc[ct] = __builtin_amdgcn_mfma_f32_16x16x32_bf16(a, b, acc[ct], 0, 0, 0);
        }
    }
    #pragma unroll
    for (int ct = 0; ct < 4; ct++) {
        int col = colbase + ct * 16 + m;
        float bcol = bias[col];
        #pragma unroll
        for (int r = 0; r < 4; r++) {
            int orow = row0 + quad * 4 + r;
            if (orow < N) outp[(size_t)orow * DIM + col] = f2bf(acc[ct][r] + bcol);
        }
    }
}

// ---------- fused attention (online softmax) + optional exp_map epilogue ----------
__global__ __launch_bounds__(256) void attn_kernel(
    const uint16_t* __restrict__ q, const uint16_t* __restrict__ k, const uint16_t* __restrict__ v,
    const int* __restrict__ row_start, const int* __restrict__ esrc,
    const float* __restrict__ curv,
    uint16_t* __restrict__ t_out,    // mode 0: h as bf16 (next layer tangent)
    float* __restrict__ x_out,       // mode 1: exp_map(h) fp32 -> d_out
    int N, int mode) {
    int wave = threadIdx.x >> 6, lane = threadIdx.x & 63;
    int n = blockIdx.x * 4 + wave;
    if (n >= N) return;
    int s0 = row_start[n], s1 = row_start[n + 1];
    uint32_t qu = ((const uint32_t*)q)[(size_t)n * (DIM / 2) + lane];
    float qa = bf2f(qu & 0xffffu), qb = bf2f(qu >> 16);
    const float inv_scale = 0.08838834764831845f;   // 1/sqrt(128)
    float mx = -INFINITY, lsum = 0.0f, ha = 0.0f, hb = 0.0f;
    for (int e = s0; e < s1; e++) {
        int s = esrc[e];
        uint32_t ku = ((const uint32_t*)k)[(size_t)s * (DIM / 2) + lane];
        float part = qa * bf2f(ku & 0xffffu) + qb * bf2f(ku >> 16);
        part = wave_reduce_add(part);
        float sc_e = part * inv_scale;
        float nm = fmaxf(mx, sc_e);
        float al = __expf(mx - nm);      // 0 on first iter (mx = -inf)
        float p = __expf(sc_e - nm);
        lsum = lsum * al + p;
        uint32_t vu = ((const uint32_t*)v)[(size_t)s * (DIM / 2) + lane];
        ha = ha * al + p * bf2f(vu & 0xffffu);
        hb = hb * al + p * bf2f(vu >> 16);
        mx = nm;
    }
    float rl = 1.0f / lsum;
    ha *= rl; hb *= rl;
    if (mode == 0) {
        uint32_t pk = (uint32_t)f2bf(ha) | ((uint32_t)f2bf(hb) << 16);
        ((uint32_t*)t_out)[(size_t)n * (DIM / 2) + lane] = pk;
    } else {
        float ss = wave_reduce_add(ha * ha + hb * hb);
        float c = curv[0];
        float sc = sqrtf(c);
        float nh = sqrtf(ss);
        float f = (nh > 1e-30f) ? tanhf(sc * nh * 0.5f) / (sc * nh) : 0.5f;
        float2 o; o.x = f * ha; o.y = f * hb;
        ((float2*)x_out)[(size_t)n * (DIM / 2) + lane] = o;
    }
}

// ---------- host ----------
extern "C" void kernel_launch(void* const* d_in, const int* in_sizes, int n_in,
                              void* d_out, int out_size, void* d_ws, size_t ws_size,
                              hipStream_t stream) {
    const float* emb  = (const float*)d_in[0];
    const float* Wq   = (const float*)d_in[1];
    const float* bq   = (const float*)d_in[2];
    const float* Wk   = (const float*)d_in[3];
    const float* bk   = (const float*)d_in[4];
    const float* Wv   = (const float*)d_in[5];
    const float* bv   = (const float*)d_in[6];
    const float* curv = (const float*)d_in[7];
    const int*   srcp = (const int*)d_in[8];
    const int*   dstp = (const int*)d_in[9];

    const int N = in_sizes[0] / DIM;
    const int L = in_sizes[2] / DIM;
    const int E = in_sizes[8];

    // workspace carve-up (256B aligned)
    uint8_t* ws = (uint8_t*)d_ws;
    size_t off = 0;
    auto carve = [&](size_t bytes) { size_t o = off; off = (off + bytes + 255) & ~(size_t)255; return o; };
    uint16_t* t_buf   = (uint16_t*)(ws + carve((size_t)N * DIM * 2));
    uint16_t* qkv_buf = (uint16_t*)(ws + carve((size_t)3 * N * DIM * 2));
    uint16_t* w_bf    = (uint16_t*)(ws + carve((size_t)L * 3 * DIM * DIM * 2));
    int* row_start    = (int*)(ws + carve((size_t)(N + 1) * 4));
    int* cnt          = (int*)(ws + carve((size_t)N * 4));
    int* cursor       = (int*)(ws + carve((size_t)N * 4));
    int* bsums        = (int*)(ws + carve(1024 * 4));
    int* esrc         = (int*)(ws + carve((size_t)E * 4));
    (void)ws_size;

    uint16_t* qb = qkv_buf;
    uint16_t* kb = qkv_buf + (size_t)N * DIM;
    uint16_t* vb = qkv_buf + (size_t)2 * N * DIM;

    // --- CSR build ---
    hipMemsetAsync(cnt, 0, (size_t)N * 4, stream);
    count_kernel<<<(E + 255) / 256, 256, 0, stream>>>(dstp, cnt, E);
    int nb = (N + SCAN_CHUNK - 1) / SCAN_CHUNK;
    scan1_kernel<<<nb, 256, 0, stream>>>(cnt, row_start, bsums, N);
    scan2_kernel<<<1, 64, 0, stream>>>(bsums, nb);
    scan3_kernel<<<(N + 255) / 256, 256, 0, stream>>>(row_start, cursor, bsums, N, E);
    scatter_kernel<<<(E + 255) / 256, 256, 0, stream>>>(srcp, dstp, cursor, esrc, E);

    // --- weights to bf16 ---
    int wtotal = L * 3 * DIM * DIM;
    convert_w_kernel<<<(wtotal + 255) / 256, 256, 0, stream>>>(Wq, Wk, Wv, w_bf, wtotal);

    // --- layer 0 tangent from embeddings ---
    tangent_kernel<<<(N + 3) / 4, 256, 0, stream>>>(emb, t_buf, curv, N);

    int strips = (N + 15) / 16;
    dim3 ggrid((strips + 3) / 4, 6);
    for (int l = 0; l < L; l++) {
        qkv_gemm_kernel<<<ggrid, 256, 0, stream>>>(
            t_buf, w_bf + (size_t)l * 3 * DIM * DIM,
            bq + (size_t)l * DIM, bk + (size_t)l * DIM, bv + (size_t)l * DIM,
            qb, kb, vb, N);
        int mode = (l == L - 1) ? 1 : 0;
        // log_map(exp_map(h)) == h exactly -> intermediate layers write h as next tangent
        attn_kernel<<<(N + 3) / 4, 256, 0, stream>>>(
            qb, kb, vb, row_start, esrc, curv, t_buf, (float*)d_out, N, mode);
    }
}

// Round 3
// 719.095 us; speedup vs baseline: 1.3068x; 1.3068x over previous
//
#include <hip/hip_runtime.h>
#include <hip/hip_bf16.h>
#include <stdint.h>

// ---------- types / helpers ----------
typedef __attribute__((ext_vector_type(8))) short short8;   // 8 fp16 (MFMA A/B frag)
typedef __attribute__((ext_vector_type(4))) float f32x4;    // MFMA C/D frag
typedef __attribute__((ext_vector_type(2))) _Float16 half2_t;

__device__ __forceinline__ uint32_t pack2(float a, float b) {
    auto r = __builtin_amdgcn_cvt_pkrtz(a, b);              // v_cvt_pkrtz_f16_f32
    return __builtin_bit_cast(uint32_t, r);
}
__device__ __forceinline__ uint16_t f2h(float x) {
    auto r = __builtin_amdgcn_cvt_pkrtz(x, 0.0f);
    return (uint16_t)(__builtin_bit_cast(uint32_t, r) & 0xffffu);
}
__device__ __forceinline__ float wave_reduce_add64(float v) {
    #pragma unroll
    for (int off = 32; off >= 1; off >>= 1) v += __shfl_xor(v, off);
    return v;
}

#define DIM 128

// ---------- CSR build ----------
__global__ void count_kernel(const int* __restrict__ dst, int* __restrict__ cnt, int E) {
    int e = blockIdx.x * blockDim.x + threadIdx.x;
    if (e < E) atomicAdd(&cnt[dst[e]], 1);
}

#define SCAN_CHUNK 2048
__global__ void scan1_kernel(const int* __restrict__ cnt, int* __restrict__ row_start,
                             int* __restrict__ bsums, int N) {
    __shared__ int lds[256];
    int tid = threadIdx.x;
    int base = blockIdx.x * SCAN_CHUNK;
    int vals[8]; int s = 0;
    #pragma unroll
    for (int i = 0; i < 8; i++) {
        int idx = base + tid * 8 + i;
        int v = (idx < N) ? cnt[idx] : 0;
        vals[i] = s; s += v;                 // local exclusive prefix
    }
    lds[tid] = s; __syncthreads();
    for (int off = 1; off < 256; off <<= 1) {
        int x = 0; if (tid >= off) x = lds[tid - off];
        __syncthreads();
        lds[tid] += x;
        __syncthreads();
    }
    int texcl = (tid > 0) ? lds[tid - 1] : 0;
    #pragma unroll
    for (int i = 0; i < 8; i++) {
        int idx = base + tid * 8 + i;
        if (idx < N) row_start[idx] = texcl + vals[i];
    }
    if (tid == 255) bsums[blockIdx.x] = lds[255];
}
// wave-parallel exclusive scan of block sums (nb can exceed 64 -> chunked)
__global__ void scan2_kernel(int* __restrict__ bsums, int nb) {
    int lane = threadIdx.x & 63;
    int run = 0;
    for (int base = 0; base < nb; base += 64) {
        int idx = base + lane;
        int orig = (idx < nb) ? bsums[idx] : 0;
        int v = orig;
        #pragma unroll
        for (int off = 1; off < 64; off <<= 1) {
            int t = __shfl_up(v, off);
            if (lane >= off) v += t;
        }
        if (idx < nb) bsums[idx] = run + v - orig;   // exclusive
        run += __shfl(v, 63);
    }
}
__global__ void scan3_kernel(int* __restrict__ row_start, int* __restrict__ cursor,
                             const int* __restrict__ bsums, int N, int E) {
    int idx = blockIdx.x * blockDim.x + threadIdx.x;
    if (idx < N) {
        int v = row_start[idx] + bsums[idx / SCAN_CHUNK];
        row_start[idx] = v;
        cursor[idx] = v;
    }
    if (idx == 0) row_start[N] = E;
}
__global__ void scatter_kernel(const int* __restrict__ src, const int* __restrict__ dst,
                               int* __restrict__ cursor, int* __restrict__ esrc, int E) {
    int e = blockIdx.x * blockDim.x + threadIdx.x;
    if (e < E) {
        int d = dst[e];
        int pos = atomicAdd(&cursor[d], 1);
        esrc[pos] = src[e];
    }
}

// ---------- weight conversion fp32 -> fp16, layout [l][mat][out_col][k] ----------
__global__ void convert_w_kernel(const float* __restrict__ Wq, const float* __restrict__ Wk,
                                 const float* __restrict__ Wv, uint16_t* __restrict__ wout,
                                 int total /* L*3*128*128 */) {
    int tid = blockIdx.x * blockDim.x + threadIdx.x;
    if (tid >= total) return;
    int per_l = 3 * DIM * DIM;
    int l = tid / per_l;
    int rem = tid % per_l;
    int mat = rem / (DIM * DIM);
    int idx = rem % (DIM * DIM);
    const float* s = (mat == 0) ? Wq : (mat == 1) ? Wk : Wv;
    wout[tid] = f2h(s[l * DIM * DIM + idx]);
}

// ---------- tangent: t = (2/sc)*atanh(sc*||x||)*x/||x||, fp16 out ----------
__global__ __launch_bounds__(256) void tangent_kernel(const float* __restrict__ x,
                                                      uint16_t* __restrict__ t,
                                                      const float* __restrict__ curv, int N) {
    int wave = threadIdx.x >> 6, lane = threadIdx.x & 63;
    int n = blockIdx.x * 4 + wave;
    if (n >= N) return;
    float2 xv = ((const float2*)(x + (size_t)n * DIM))[lane];
    float ss = xv.x * xv.x + xv.y * xv.y;
    ss = wave_reduce_add64(ss);
    float c = curv[0];
    float sc = sqrtf(c);
    float r = sqrtf(ss);
    float f = (r > 1e-30f) ? (2.0f / sc) * atanhf(sc * r) / r : 2.0f;
    ((uint32_t*)t)[(size_t)n * (DIM / 2) + lane] = pack2(f * xv.x, f * xv.y);
}

// ---------- QKV GEMM: out[node][col] ; A = W rows (cols of output), B = t rows ----------
// D row (quad*4+r) = w_col within tile; D col (lane&15) = node  -> 4 consecutive dims
// per lane -> packed 8B stores.
__global__ __launch_bounds__(256) void qkv_gemm_kernel(
    const uint16_t* __restrict__ t,    // [N,128] fp16
    const uint16_t* __restrict__ w,    // [3][128][128] fp16 (this layer)
    const float* __restrict__ bq, const float* __restrict__ bk, const float* __restrict__ bv,
    uint16_t* __restrict__ qkv,        // [3][N][128] fp16
    int N) {
    int wave = threadIdx.x >> 6, lane = threadIdx.x & 63;
    int sub = lane & 15, quad = lane >> 4;
    int mat = blockIdx.y;
    const uint16_t* wm = w + (size_t)mat * DIM * DIM;
    const float* bias = (mat == 0) ? bq : (mat == 1) ? bk : bv;
    uint16_t* outp = qkv + (size_t)mat * N * DIM;
    int node = (blockIdx.x * 4 + wave) * 16 + sub;
    int nodec = (node < N) ? node : (N - 1);
    f32x4 acc[8] = {};
    #pragma unroll
    for (int k0 = 0; k0 < DIM; k0 += 32) {
        short8 b = *(const short8*)(t + (size_t)nodec * DIM + k0 + quad * 8);
        #pragma unroll
        for (int tile = 0; tile < 8; tile++) {
            short8 a = *(const short8*)(wm + (size_t)(tile * 16 + sub) * DIM + k0 + quad * 8);
            acc[tile] = __builtin_amdgcn_mfma_f32_16x16x32_f16(a, b, acc[tile], 0, 0, 0);
        }
    }
    if (node < N) {
        #pragma unroll
        for (int tile = 0; tile < 8; tile++) {
            float4 bs = *(const float4*)(bias + tile * 16 + quad * 4);
            uint2 pk;
            pk.x = pack2(acc[tile][0] + bs.x, acc[tile][1] + bs.y);
            pk.y = pack2(acc[tile][2] + bs.z, acc[tile][3] + bs.w);
            *(uint2*)(outp + (size_t)node * DIM + tile * 16 + quad * 4) = pk;
        }
    }
}

// ---------- fused attention: quarter-wave per edge, 4 edges in flight ----------
__global__ __launch_bounds__(256) void attn_kernel(
    const uint16_t* __restrict__ q, const uint16_t* __restrict__ k, const uint16_t* __restrict__ v,
    const int* __restrict__ row_start, const int* __restrict__ esrc,
    const float* __restrict__ curv,
    uint16_t* __restrict__ t_out,    // mode 0: h as fp16 (next layer tangent)
    float* __restrict__ x_out,       // mode 1: exp_map(h) fp32 -> d_out
    int N, int mode) {
    int wave = threadIdx.x >> 6, lane = threadIdx.x & 63;
    int sub = lane & 15, quad = lane >> 4;
    int n = blockIdx.x * 4 + wave;
    if (n >= N) return;
    int s0 = row_start[n], s1 = row_start[n + 1];
    int deg = s1 - s0;
    int nit = (deg + 3) >> 2;
    // q fragment: 8 dims per lane (dims sub*8 .. sub*8+7), replicated across quads
    uint4 qu = *(const uint4*)(q + (size_t)n * DIM + sub * 8);
    half2_t qh[4];
    #pragma unroll
    for (int i = 0; i < 4; i++) qh[i] = __builtin_bit_cast(half2_t, ((const uint32_t*)&qu)[i]);
    const float inv_scale = 0.08838834764831845f;   // 1/sqrt(128)
    float m = -1e30f, l = 0.0f;
    float h[8] = {0, 0, 0, 0, 0, 0, 0, 0};
    for (int it = 0; it < nit; it++) {
        int e = s0 + it * 4 + quad;
        bool valid = (e < s1);
        int sidx = esrc[valid ? e : s0];
        const uint16_t* krow = k + (size_t)sidx * DIM + sub * 8;
        const uint16_t* vrow = v + (size_t)sidx * DIM + sub * 8;
        uint4 ku = *(const uint4*)krow;
        uint4 vu = *(const uint4*)vrow;
        float dot = 0.0f;
        #pragma unroll
        for (int i = 0; i < 4; i++)
            dot = __builtin_amdgcn_fdot2(qh[i],
                      __builtin_bit_cast(half2_t, ((const uint32_t*)&ku)[i]), dot, false);
        #pragma unroll
        for (int off = 8; off >= 1; off >>= 1) dot += __shfl_xor(dot, off);
        float sc_e = valid ? dot * inv_scale : -1e30f;
        float nm = fmaxf(m, sc_e);
        float al = __expf(m - nm);                    // 1 when nothing yet (l,h are 0)
        float p = valid ? __expf(sc_e - nm) : 0.0f;
        l = l * al + p;
        #pragma unroll
        for (int i = 0; i < 4; i++) {
            half2_t vh = __builtin_bit_cast(half2_t, ((const uint32_t*)&vu)[i]);
            h[2 * i]     = h[2 * i]     * al + p * (float)vh.x;
            h[2 * i + 1] = h[2 * i + 1] * al + p * (float)vh.y;
        }
        m = nm;
    }
    // merge the 4 quarter states (flash merge), xor 16 then xor 32
    #pragma unroll
    for (int off = 16; off <= 32; off <<= 1) {
        float m2 = __shfl_xor(m, off);
        float l2 = __shfl_xor(l, off);
        float nm = fmaxf(m, m2);
        float a1 = __expf(m - nm), a2 = __expf(m2 - nm);
        l = l * a1 + l2 * a2;
        #pragma unroll
        for (int j = 0; j < 8; j++) {
            float h2 = __shfl_xor(h[j], off);
            h[j] = h[j] * a1 + h2 * a2;
        }
        m = nm;
    }
    float rl = 1.0f / l;
    #pragma unroll
    for (int j = 0; j < 8; j++) h[j] *= rl;
    if (mode == 0) {
        if (quad == 0) {
            uint4 pk;
            pk.x = pack2(h[0], h[1]); pk.y = pack2(h[2], h[3]);
            pk.z = pack2(h[4], h[5]); pk.w = pack2(h[6], h[7]);
            *(uint4*)(t_out + (size_t)n * DIM + sub * 8) = pk;
        }
    } else {
        float ss = 0.0f;
        #pragma unroll
        for (int j = 0; j < 8; j++) ss += h[j] * h[j];
        #pragma unroll
        for (int off = 8; off >= 1; off >>= 1) ss += __shfl_xor(ss, off);
        float c = curv[0];
        float sc = sqrtf(c);
        float nh = sqrtf(ss);
        float f = (nh > 1e-30f) ? tanhf(sc * nh * 0.5f) / (sc * nh) : 0.5f;
        if (quad == 0) {
            float4 o0 = {f * h[0], f * h[1], f * h[2], f * h[3]};
            float4 o1 = {f * h[4], f * h[5], f * h[6], f * h[7]};
            *(float4*)(x_out + (size_t)n * DIM + sub * 8)     = o0;
            *(float4*)(x_out + (size_t)n * DIM + sub * 8 + 4) = o1;
        }
    }
}

// ---------- host ----------
extern "C" void kernel_launch(void* const* d_in, const int* in_sizes, int n_in,
                              void* d_out, int out_size, void* d_ws, size_t ws_size,
                              hipStream_t stream) {
    const float* emb  = (const float*)d_in[0];
    const float* Wq   = (const float*)d_in[1];
    const float* bq   = (const float*)d_in[2];
    const float* Wk   = (const float*)d_in[3];
    const float* bk   = (const float*)d_in[4];
    const float* Wv   = (const float*)d_in[5];
    const float* bv   = (const float*)d_in[6];
    const float* curv = (const float*)d_in[7];
    const int*   srcp = (const int*)d_in[8];
    const int*   dstp = (const int*)d_in[9];

    const int N = in_sizes[0] / DIM;
    const int L = in_sizes[2] / DIM;
    const int E = in_sizes[8];

    uint8_t* ws = (uint8_t*)d_ws;
    size_t off = 0;
    auto carve = [&](size_t bytes) { size_t o = off; off = (off + bytes + 255) & ~(size_t)255; return o; };
    uint16_t* t_buf   = (uint16_t*)(ws + carve((size_t)N * DIM * 2));
    uint16_t* qkv_buf = (uint16_t*)(ws + carve((size_t)3 * N * DIM * 2));
    uint16_t* w_h     = (uint16_t*)(ws + carve((size_t)L * 3 * DIM * DIM * 2));
    int* row_start    = (int*)(ws + carve((size_t)(N + 1) * 4));
    int* cnt          = (int*)(ws + carve((size_t)N * 4));
    int* cursor       = (int*)(ws + carve((size_t)N * 4));
    int* bsums        = (int*)(ws + carve(1024 * 4));
    int* esrc         = (int*)(ws + carve((size_t)E * 4));
    (void)ws_size;

    uint16_t* qb = qkv_buf;
    uint16_t* kb = qkv_buf + (size_t)N * DIM;
    uint16_t* vb = qkv_buf + (size_t)2 * N * DIM;

    // --- CSR build ---
    (void)hipMemsetAsync(cnt, 0, (size_t)N * 4, stream);
    count_kernel<<<(E + 255) / 256, 256, 0, stream>>>(dstp, cnt, E);
    int nb = (N + SCAN_CHUNK - 1) / SCAN_CHUNK;
    scan1_kernel<<<nb, 256, 0, stream>>>(cnt, row_start, bsums, N);
    scan2_kernel<<<1, 64, 0, stream>>>(bsums, nb);
    scan3_kernel<<<(N + 255) / 256, 256, 0, stream>>>(row_start, cursor, bsums, N, E);
    scatter_kernel<<<(E + 255) / 256, 256, 0, stream>>>(srcp, dstp, cursor, esrc, E);

    // --- weights to fp16 ---
    int wtotal = L * 3 * DIM * DIM;
    convert_w_kernel<<<(wtotal + 255) / 256, 256, 0, stream>>>(Wq, Wk, Wv, w_h, wtotal);

    // --- layer 0 tangent from embeddings ---
    tangent_kernel<<<(N + 3) / 4, 256, 0, stream>>>(emb, t_buf, curv, N);

    dim3 ggrid(((N + 63) / 64), 3);
    for (int l = 0; l < L; l++) {
        qkv_gemm_kernel<<<ggrid, 256, 0, stream>>>(
            t_buf, w_h + (size_t)l * 3 * DIM * DIM,
            bq + (size_t)l * DIM, bk + (size_t)l * DIM, bv + (size_t)l * DIM,
            qkv_buf, N);
        int mode = (l == L - 1) ? 1 : 0;
        // log_map(exp_map(h)) == h exactly -> intermediate layer writes h as next tangent
        attn_kernel<<<(N + 3) / 4, 256, 0, stream>>>(
            qb, kb, vb, row_start, esrc, curv, t_buf, (float*)d_out, N, mode);
    }
}